// Round 7
// baseline (517.501 us; speedup 1.0000x reference)
//
#include <hip/hip_runtime.h>
#include <stdint.h>

#define T_SEQ 2048
#define C_DIM 2048
#define NH    16
#define HD    128

typedef __attribute__((ext_vector_type(8))) short short8;
typedef __attribute__((ext_vector_type(4))) float f32x4;

#if defined(__has_builtin)
# if __has_builtin(__builtin_amdgcn_global_load_lds)
#  define HAVE_GLL 1
# endif
#endif
#ifndef HAVE_GLL
# define HAVE_GLL 0
#endif

__device__ __forceinline__ short f2bf(float f) {
    uint32_t x = __float_as_uint(f);
    uint32_t r = (x + 0x7fffu + ((x >> 16) & 1u)) >> 16;   // RNE
    return (short)r;
}
__device__ __forceinline__ float bf2f(short s) {
    return __uint_as_float(((uint32_t)(unsigned short)s) << 16);
}

// async global->LDS, 16B/lane; LDS dst is wave-uniform base, HW adds lane*16.
__device__ __forceinline__ void gload16(const short* g, short* l) {
    const int lane = threadIdx.x & 63;
#if HAVE_GLL
    __builtin_amdgcn_global_load_lds(
        (const __attribute__((address_space(1))) void*)(g + lane * 8),
        (__attribute__((address_space(3))) void*)l, 16, 0, 0);
#else
    *(short8*)(l + lane * 8) = *(const short8*)(g + lane * 8);
#endif
}

// ============ prep A-side: fp32 [M][K] -> fragment-ordered bf16 tiles ============
// tile (mblk,kb) = 128 rows x 32 k; layout [fm=row>>4][lane=(kc<<4)|(row&15)][j=k&7]
__global__ __launch_bounds__(256) void prep_a(
    const float* __restrict__ X, short* __restrict__ Apk, int K, int split)
{
    const int kb = blockIdx.x, mblk = blockIdx.y, tid = threadIdx.x;
    const int kpb = K / 32;
    const int nkb = kpb << split;
    const size_t hiBase = ((size_t)mblk * nkb + kb) * 4096;
    const size_t loBase = hiBase + (size_t)kpb * 4096;
#pragma unroll
    for (int itr = 0; itr < 2; ++itr) {
        const int item = itr * 256 + tid;          // 0..511 = 128 rows x 4 kchunks
        const int row = item >> 2, kc = item & 3;
        const float* xp = &X[(size_t)(mblk * 128 + row) * K + kb * 32 + kc * 8];
        float4 v0 = *(const float4*)xp;
        float4 v1 = *(const float4*)(xp + 4);
        float f[8] = { v0.x, v0.y, v0.z, v0.w, v1.x, v1.y, v1.z, v1.w };
        const size_t off = (size_t)(row >> 4) * 512 + (size_t)((kc << 4) | (row & 15)) * 8;
        short h[8];
#pragma unroll
        for (int j = 0; j < 8; ++j) h[j] = f2bf(f[j]);
        int hw[4];
#pragma unroll
        for (int j = 0; j < 4; ++j) hw[j] = (h[2*j] & 0xffff) | (h[2*j+1] << 16);
        *(int4*)&Apk[hiBase + off] = make_int4(hw[0], hw[1], hw[2], hw[3]);
        if (split) {
            int lw[4];
#pragma unroll
            for (int j = 0; j < 4; ++j) {
                short a = f2bf(f[2*j]   - bf2f(h[2*j]));
                short b = f2bf(f[2*j+1] - bf2f(h[2*j+1]));
                lw[j] = (a & 0xffff) | (b << 16);
            }
            *(int4*)&Apk[loBase + off] = make_int4(lw[0], lw[1], lw[2], lw[3]);
        }
    }
}

// ============ prep B-side: fp32 [K][N] -> fragment-ordered bf16 tiles (transposed) ============
__global__ __launch_bounds__(256) void prep_b(
    const float* __restrict__ W, short* __restrict__ Bpk, int K, int N, int split)
{
    const int kb = blockIdx.x, nblk = blockIdx.y, tid = threadIdx.x;
    const int kpb = K / 32;
    const int nkb = kpb << split;
    __shared__ float Ws[32][129];
    {
        const int r = tid >> 3, cbase = (tid & 7) * 4;
#pragma unroll
        for (int itc = 0; itc < 4; ++itc) {
            const int c = cbase + itc * 32;
            const float4 v = *(const float4*)&W[(size_t)(kb * 32 + r) * N + nblk * 128 + c];
            Ws[r][c] = v.x; Ws[r][c + 1] = v.y; Ws[r][c + 2] = v.z; Ws[r][c + 3] = v.w;
        }
    }
    __syncthreads();
    const size_t hiBase = ((size_t)nblk * nkb + kb) * 4096;
    const size_t loBase = hiBase + (size_t)kpb * 4096;
#pragma unroll
    for (int itr = 0; itr < 2; ++itr) {
        const int item = itr * 256 + tid;
        const int n = item >> 2, kc = item & 3;
        float f[8];
#pragma unroll
        for (int j = 0; j < 8; ++j) f[j] = Ws[kc * 8 + j][n];
        const size_t off = (size_t)(n >> 4) * 512 + (size_t)((kc << 4) | (n & 15)) * 8;
        short h[8];
#pragma unroll
        for (int j = 0; j < 8; ++j) h[j] = f2bf(f[j]);
        int hw[4];
#pragma unroll
        for (int j = 0; j < 4; ++j) hw[j] = (h[2*j] & 0xffff) | (h[2*j+1] << 16);
        *(int4*)&Bpk[hiBase + off] = make_int4(hw[0], hw[1], hw[2], hw[3]);
        if (split) {
            int lw[4];
#pragma unroll
            for (int j = 0; j < 4; ++j) {
                short a = f2bf(f[2*j]   - bf2f(h[2*j]));
                short b = f2bf(f[2*j+1] - bf2f(h[2*j+1]));
                lw[j] = (a & 0xffff) | (b << 16);
            }
            *(int4*)&Bpk[loBase + off] = make_int4(lw[0], lw[1], lw[2], lw[3]);
        }
    }
}

// ============ bf16 MFMA GEMM: ring-of-4 DMA + m201-style 16-MFMA phases ============
// BM=256, BN=128*BNP, BK=32/step, 8 waves. Per step (BNP=2): two phases of
// {ds_read subtile + 2 gloads -> barrier -> lgkmcnt(0) -> setprio 16 MFMA -> barrier}.
// Counted vmcnt once per step (never 0 in steady state). Fragment-ordered tiles:
// all ds_read_b128 lane-linear (conflict-free); gload dest linear.
// mode: 0 = plain bf16; 1 = 3-term split (Ahi@Bhi|Ahi@Blo|Alo@Bhi, nkb=192);
//       2 = 2-term split (Ahi@Bhi|Ahi@Blo, nkb=128, A hi-only).
// Race proof (ring 4, prefetch 3): reads of slot t-1 complete before that wave leaves
// iter t-1 (lgkm-gated pre-MFMA); stage(t+3) is issued after iter t's publish barrier,
// hence after ALL waves' slot t-1 reads. DMA writes only slot (t+3)&3.
template<int BNP>
__global__ __launch_bounds__(512, 2) void gemm_bf16_256(
    const short* __restrict__ Apk, const short* __restrict__ Bpk,
    float* __restrict__ C, int N, int gy, int nkbA, int nkbB, int nkb, int mode)
{
    constexpr int NT    = 2 + BNP;        // tiles per step (A0,A1,B0[,B1])
    constexpr int STEPB = NT * 8192;      // bytes per step buffer
    constexpr int MR    = 4 * BNP;        // m-frags per wave
    constexpr int WC    = 2 * BNP;        // wave columns
    __shared__ __align__(16) char smem[4 * STEPB];   // 128 KB (BNP=2) / 96 KB (BNP=1)

    const int tid = threadIdx.x;
    const int lane = tid & 63, w = tid >> 6;
    const int r16 = lane & 15;
    const int wr = w / WC, wc = w % WC;

    // bijective XCD swizzle (nwg % 8 == 0)
    const int nwg = gridDim.x, cpx = nwg >> 3, bid = blockIdx.x;
    const int swz = (bid & 7) * cpx + (bid >> 3);
    const int by = swz % gy, bx = swz / gy;
    const int bm = by * 256, bn = bx * (BNP * 128);
    const size_t Abase = (size_t)(2 * by) * nkbA * 4096;
    const size_t Bbase = (size_t)(BNP * bx) * nkbB * 4096;

    f32x4 acc[MR][4];
#pragma unroll
    for (int m = 0; m < MR; ++m)
#pragma unroll
        for (int n = 0; n < 4; ++n) acc[m][n] = (f32x4){0.f, 0.f, 0.f, 0.f};

    // stage one half (2 gloads) for BNP=2, or all 3 for BNP=1
    auto stage_half = [&](int vkb, int half) {
        const int bi = vkb & 3;
        int akb, bkb;
        if (mode == 1)      { akb = (vkb < 64) ? vkb : vkb - 64; bkb = (vkb < 128) ? vkb : vkb - 128; }
        else if (mode == 2) { akb = (vkb < 64) ? vkb : vkb - 64; bkb = vkb; }
        else                { akb = vkb; bkb = vkb; }
        const int i0 = (BNP == 2) ? half * 2 : 0;
        const int i1 = (BNP == 2) ? half * 2 + 2 : NT;
#pragma unroll
        for (int i = i0; i < i1; ++i) {
            const int o = (w * NT + i) * 1024;           // byte offset within step buffer
            const int tileIdx = o >> 13;                 // 8 KB per tile
            const int inTile = (o & 8191) >> 1;          // shorts
            const short* g = (tileIdx < 2)
                ? Apk + Abase + ((size_t)tileIdx * nkbA + akb) * 4096 + inTile
                : Bpk + Bbase + ((size_t)(tileIdx - 2) * nkbB + bkb) * 4096 + inTile;
            gload16(g, (short*)(smem + bi * STEPB + o));
        }
    };
    auto stage_full = [&](int vkb) {
        stage_half(vkb, 0);
        if (BNP == 2) stage_half(vkb, 1);
    };

    stage_full(0); stage_full(1); stage_full(2);   // depth-3 prefetch into 4-deep ring
    __builtin_amdgcn_sched_barrier(0);

    for (int t = 0; t < nkb; ++t) {
        const int rem = nkb - 1 - t;
        if (BNP == 2) {
            if (rem >= 2)      asm volatile("s_waitcnt vmcnt(8)" ::: "memory");
            else if (rem == 1) asm volatile("s_waitcnt vmcnt(4)" ::: "memory");
            else               asm volatile("s_waitcnt vmcnt(0)" ::: "memory");
        } else {
            if (rem >= 2)      asm volatile("s_waitcnt vmcnt(6)" ::: "memory");
            else if (rem == 1) asm volatile("s_waitcnt vmcnt(3)" ::: "memory");
            else               asm volatile("s_waitcnt vmcnt(0)" ::: "memory");
        }
        __builtin_amdgcn_s_barrier();      // publish buf[t&3]; slot t-1 reads all done
        __builtin_amdgcn_sched_barrier(0);

        const char* buf = smem + (t & 3) * STEPB;
        const bool pf = (t + 3 < nkb);

        if (BNP == 2) {
            // ---- phase 0: B all + A lower half, 16 MFMA ----
            short8 af[4], bfr[4];
#pragma unroll
            for (int n = 0; n < 4; ++n) {
                const int fn = wc * 4 + n;
                bfr[n] = *(const short8*)(buf + 16384 + (fn >> 3) * 8192 + (fn & 7) * 1024 + lane * 16);
            }
#pragma unroll
            for (int m = 0; m < 4; ++m) {
                const int fm = wr * 8 + m;
                af[m] = *(const short8*)(buf + (fm >> 3) * 8192 + (fm & 7) * 1024 + lane * 16);
            }
            if (pf) stage_half(t + 3, 0);
            __builtin_amdgcn_s_barrier();
            asm volatile("s_waitcnt lgkmcnt(0)" ::: "memory");
            __builtin_amdgcn_sched_barrier(0);
            __builtin_amdgcn_s_setprio(1);
#pragma unroll
            for (int m = 0; m < 4; ++m)
#pragma unroll
                for (int n = 0; n < 4; ++n)
                    acc[m][n] = __builtin_amdgcn_mfma_f32_16x16x32_bf16(af[m], bfr[n], acc[m][n], 0, 0, 0);
            __builtin_amdgcn_s_setprio(0);
            __builtin_amdgcn_s_barrier();

            // ---- phase 1: A upper half, 16 MFMA (bfr held in regs) ----
            short8 af2[4];
#pragma unroll
            for (int m = 0; m < 4; ++m) {
                const int fm = wr * 8 + 4 + m;
                af2[m] = *(const short8*)(buf + (fm >> 3) * 8192 + (fm & 7) * 1024 + lane * 16);
            }
            if (pf) stage_half(t + 3, 1);
            __builtin_amdgcn_s_barrier();
            asm volatile("s_waitcnt lgkmcnt(0)" ::: "memory");
            __builtin_amdgcn_sched_barrier(0);
            __builtin_amdgcn_s_setprio(1);
#pragma unroll
            for (int m = 0; m < 4; ++m)
#pragma unroll
                for (int n = 0; n < 4; ++n)
                    acc[4 + m][n] = __builtin_amdgcn_mfma_f32_16x16x32_bf16(af2[m], bfr[n], acc[4 + m][n], 0, 0, 0);
            __builtin_amdgcn_s_setprio(0);
            __builtin_amdgcn_s_barrier();
        } else {
            // ---- single phase: 16 MFMA ----
            short8 af[4], bfr[4];
#pragma unroll
            for (int n = 0; n < 4; ++n) {
                const int fn = wc * 4 + n;
                bfr[n] = *(const short8*)(buf + 16384 + (fn >> 3) * 8192 + (fn & 7) * 1024 + lane * 16);
            }
#pragma unroll
            for (int m = 0; m < 4; ++m) {
                const int fm = wr * 4 + m;
                af[m] = *(const short8*)(buf + (fm >> 3) * 8192 + (fm & 7) * 1024 + lane * 16);
            }
            if (pf) stage_half(t + 3, 0);
            __builtin_amdgcn_s_barrier();
            asm volatile("s_waitcnt lgkmcnt(0)" ::: "memory");
            __builtin_amdgcn_sched_barrier(0);
            __builtin_amdgcn_s_setprio(1);
#pragma unroll
            for (int m = 0; m < 4; ++m)
#pragma unroll
                for (int n = 0; n < 4; ++n)
                    acc[m][n] = __builtin_amdgcn_mfma_f32_16x16x32_bf16(af[m], bfr[n], acc[m][n], 0, 0, 0);
            __builtin_amdgcn_s_setprio(0);
            __builtin_amdgcn_s_barrier();
        }
    }

    // ---- epilogue: per-wave private LDS bounce (stride 68), float4 coalesced stores ----
    __builtin_amdgcn_s_barrier();          // all waves out of K-loop before smem reuse
    float* Cs = (float*)(smem + w * 4352); // 16 rows x 68 f32 per wave
    const int rq = lane >> 4;
#pragma unroll
    for (int m = 0; m < MR; ++m) {
#pragma unroll
        for (int n = 0; n < 4; ++n)
#pragma unroll
            for (int j = 0; j < 4; ++j)
                Cs[(rq * 4 + j) * 68 + n * 16 + r16] = acc[m][n][j];
#pragma unroll
        for (int it2 = 0; it2 < 4; ++it2) {
            const int r = it2 * 4 + rq;
            const float4 v = *(const float4*)&Cs[r * 68 + r16 * 4];
            const int grow = bm + wr * (MR * 16) + m * 16 + r;
            *(float4*)&C[(size_t)grow * N + bn + wc * 64 + r16 * 4] = v;
        }
    }
}

// ===================== conv3 + rmsnorm + rope -> bf16 q,k (scale folded), bf16 V^T, fp32 intent ==========
__global__ __launch_bounds__(128) void conv_norm_rope(
    const float* __restrict__ qkv,
    const float* __restrict__ wq, const float* __restrict__ wk,
    const float* __restrict__ wv, const float* __restrict__ wi,
    const float* __restrict__ qnw, const float* __restrict__ knw,
    const float* __restrict__ cosT, const float* __restrict__ sinT,
    short* __restrict__ qt, short* __restrict__ kt,
    short* __restrict__ vtt, float* __restrict__ it)
{
    const int t = blockIdx.x, h = blockIdx.y, b = blockIdx.z;
    const int d = threadIdx.x;
    const int c = h * HD + d;
    const size_t rowbase = ((size_t)(b * T_SEQ + t)) * (4 * C_DIM);

    const float* Wt[4] = { wq, wk, wv, wi };
    float z[4];
#pragma unroll
    for (int s = 0; s < 4; ++s) {
        const float* w = Wt[s] + c * 3;
        float w0 = w[0], w1 = w[1], w2 = w[2];
        size_t idx = rowbase + (size_t)s * C_DIM + c;
        float x0 = qkv[idx];
        float x1 = (t >= 1) ? qkv[idx - (size_t)4 * C_DIM] : 0.f;
        float x2 = (t >= 2) ? qkv[idx - (size_t)8 * C_DIM] : 0.f;
        z[s] = fmaf(w0, x2, fmaf(w1, x1, w2 * x0));
    }

    float sq = z[0] * z[0], sk = z[1] * z[1];
#pragma unroll
    for (int off = 32; off > 0; off >>= 1) {
        sq += __shfl_down(sq, off);
        sk += __shfl_down(sk, off);
    }
    __shared__ float red[4];
    const int wid = threadIdx.x >> 6, lane = threadIdx.x & 63;
    if (lane == 0) { red[wid * 2 + 0] = sq; red[wid * 2 + 1] = sk; }
    __syncthreads();
    const float rq = rsqrtf((red[0] + red[2]) * (1.f / HD) + 1e-5f);
    const float rk = rsqrtf((red[1] + red[3]) * (1.f / HD) + 1e-5f);

    float zq = z[0] * rq * qnw[d];
    float zk = z[1] * rk * knw[d];
    float pq = __shfl_xor(zq, 1);
    float pk = __shfl_xor(zk, 1);
    float cv = cosT[t * (HD / 2) + (d >> 1)];
    float sv = sinT[t * (HD / 2) + (d >> 1)];
    float oq = (d & 1) ? (pq * sv + zq * cv) : (zq * cv - pq * sv);
    float ok = (d & 1) ? (pk * sv + zk * cv) : (zk * cv - pk * sv);
    oq *= 0.08838834764831845f;   // fold 1/sqrt(128) into q

    size_t o = ((size_t)(b * NH + h) * T_SEQ + t) * HD + d;
    qt[o] = f2bf(oq);
    kt[o] = f2bf(ok);
    vtt[((size_t)(b * NH + h) * HD + d) * T_SEQ + t] = f2bf(z[2]);   // V transposed [bh][d][t]
    it[o] = z[3];
}

// ===================== bf16 MFMA causal flash attention + sigmoid gate (unchanged) ==========
__global__ __launch_bounds__(256, 3) void flash_mfma(
    const short* __restrict__ qt, const short* __restrict__ kt,
    const short* __restrict__ vtt, const float* __restrict__ it,
    float* __restrict__ y)
{
    __shared__ short lds_k[8192];
    __shared__ short lds_v[8192];
    __shared__ short lds_p[4096];

    const int tid = threadIdx.x;
    const int lane = tid & 63, w = tid >> 6;
    const int r16 = lane & 15, g = lane >> 4;

    const int blk = blockIdx.x;
    const int xcd = blk & 7, idx = blk >> 3;
    const int bh = xcd * 4 + (idx & 3);
    const int qt_i = 31 - (idx >> 2);
    const int b = bh >> 4, h = bh & 15;
    const int q0 = qt_i * 64;
    const int qrow = q0 + w * 16;

    char* KsB = (char*)lds_k;
    char* VsB = (char*)lds_v;
    char* PsB = (char*)lds_p + w * 2048;

    short8 qf[4];
    {
        const short* qp = qt + ((size_t)bh * T_SEQ + qrow + r16) * HD;
#pragma unroll
        for (int kc = 0; kc < 4; ++kc)
            qf[kc] = *(const short8*)(qp + kc * 32 + g * 8);
    }

    f32x4 o[8];
    float m[4], l[4];
#pragma unroll
    for (int dn = 0; dn < 8; ++dn) o[dn] = (f32x4){0.f, 0.f, 0.f, 0.f};
#pragma unroll
    for (int j = 0; j < 4; ++j) { m[j] = -1e30f; l[j] = 0.f; }

    const short* kbh = kt + (size_t)bh * T_SEQ * HD;
    const short* vbh = vtt + (size_t)bh * HD * T_SEQ;

    for (int kti = 0; kti <= qt_i; ++kti) {
        const int k0 = kti * 64;
        __syncthreads();
#pragma unroll
        for (int i = 0; i < 4; ++i) {
            const int ix = tid + i * 256;
            const int row = ix >> 4, dch = ix & 15;
            short8 v = *(const short8*)(kbh + (size_t)(k0 + row) * HD + dch * 8);
            *(short8*)(KsB + row * 256 + ((dch * 16) ^ ((row & 7) << 4))) = v;
        }
#pragma unroll
        for (int i = 0; i < 4; ++i) {
            const int ix = tid + i * 256;
            const int dr = ix >> 3, kch = ix & 7;
            short8 v = *(const short8*)(vbh + (size_t)dr * T_SEQ + k0 + kch * 8);
            *(short8*)(VsB + dr * 128 + ((kch * 16) ^ ((dr & 7) << 4))) = v;
        }
        __syncthreads();

        f32x4 sacc[4];
#pragma unroll
        for (int nt = 0; nt < 4; ++nt) sacc[nt] = (f32x4){0.f, 0.f, 0.f, 0.f};
        __builtin_amdgcn_s_setprio(1);
#pragma unroll
        for (int nt = 0; nt < 4; ++nt) {
            const int key = nt * 16 + r16;
#pragma unroll
            for (int kc = 0; kc < 4; ++kc) {
                const short8 kf = *(const short8*)(KsB + key * 256 +
                                    ((kc * 64 + g * 16) ^ ((r16 & 7) << 4)));
                sacc[nt] = __builtin_amdgcn_mfma_f32_16x16x32_bf16(qf[kc], kf, sacc[nt], 0, 0, 0);
            }
        }
        __builtin_amdgcn_s_setprio(0);

        const bool diag = (kti == qt_i);
#pragma unroll
        for (int j = 0; j < 4; ++j) {
            const int qi = qrow + g * 4 + j;
            float s0 = sacc[0][j], s1 = sacc[1][j], s2 = sacc[2][j], s3 = sacc[3][j];
            if (diag) {
                if (k0 +      r16 > qi) s0 = -1e30f;
                if (k0 + 16 + r16 > qi) s1 = -1e30f;
                if (k0 + 32 + r16 > qi) s2 = -1e30f;
                if (k0 + 48 + r16 > qi) s3 = -1e30f;
            }
            float mx = fmaxf(fmaxf(s0, s1), fmaxf(s2, s3));
            mx = fmaxf(mx, __shfl_xor(mx, 1));
            mx = fmaxf(mx, __shfl_xor(mx, 2));
            mx = fmaxf(mx, __shfl_xor(mx, 4));
            mx = fmaxf(mx, __shfl_xor(mx, 8));
            const float mn = fmaxf(m[j], mx);
            const float corr = __expf(m[j] - mn);
            m[j] = mn;
            float p0 = __expf(s0 - mn), p1 = __expf(s1 - mn);
            float p2 = __expf(s2 - mn), p3 = __expf(s3 - mn);
            float ps = p0 + p1 + p2 + p3;
            ps += __shfl_xor(ps, 1);
            ps += __shfl_xor(ps, 2);
            ps += __shfl_xor(ps, 4);
            ps += __shfl_xor(ps, 8);
            l[j] = l[j] * corr + ps;
#pragma unroll
            for (int dn = 0; dn < 8; ++dn) o[dn][j] *= corr;
            const int row = g * 4 + j;
            const int rsw = (row & 7) << 4;
            *(short*)(PsB + row * 128 + ((0  + r16 * 2) ^ rsw)) = f2bf(p0);
            *(short*)(PsB + row * 128 + ((32 + r16 * 2) ^ rsw)) = f2bf(p1);
            *(short*)(PsB + row * 128 + ((64 + r16 * 2) ^ rsw)) = f2bf(p2);
            *(short*)(PsB + row * 128 + ((96 + r16 * 2) ^ rsw)) = f2bf(p3);
        }

        short8 pf[2];
#pragma unroll
        for (int kc2 = 0; kc2 < 2; ++kc2)
            pf[kc2] = *(const short8*)(PsB + r16 * 128 +
                        ((kc2 * 64 + g * 16) ^ ((r16 & 7) << 4)));
        __builtin_amdgcn_s_setprio(1);
#pragma unroll
        for (int dn = 0; dn < 8; ++dn) {
            const int d = dn * 16 + r16;
#pragma unroll
            for (int kc2 = 0; kc2 < 2; ++kc2) {
                const short8 vf = *(const short8*)(VsB + d * 128 +
                                    ((kc2 * 64 + g * 16) ^ ((r16 & 7) << 4)));
                o[dn] = __builtin_amdgcn_mfma_f32_16x16x32_bf16(pf[kc2], vf, o[dn], 0, 0, 0);
            }
        }
        __builtin_amdgcn_s_setprio(0);
    }

#pragma unroll
    for (int j = 0; j < 4; ++j) {
        const float inv = 1.f / l[j];
        const int t = qrow + g * 4 + j;
        const float* ip = it + ((size_t)bh * T_SEQ + t) * HD;
        float* yp = y + ((size_t)(b * T_SEQ + t)) * C_DIM + h * HD;
#pragma unroll
        for (int dn = 0; dn < 8; ++dn) {
            const int d = dn * 16 + r16;
            const float gate = 1.f / (1.f + __expf(-ip[d]));
            yp[d] = o[dn][j] * inv * gate;
        }
    }
}

// ===================== launch =====================
extern "C" void kernel_launch(void* const* d_in, const int* in_sizes, int n_in,
                              void* d_out, int out_size, void* d_ws, size_t ws_size,
                              hipStream_t stream)
{
    const float* x     = (const float*)d_in[0];
    const float* cosT  = (const float*)d_in[1];
    const float* sinT  = (const float*)d_in[2];
    const float* Wqkv  = (const float*)d_in[3];
    const float* wq    = (const float*)d_in[4];
    const float* wk    = (const float*)d_in[5];
    const float* wv    = (const float*)d_in[6];
    const float* wi    = (const float*)d_in[7];
    const float* qnw   = (const float*)d_in[8];
    const float* knw   = (const float*)d_in[9];
    const float* Wproj = (const float*)d_in[10];
    float* out = (float*)d_out;

    char* ws = (char*)d_ws;
    const size_t MiB = 1048576;
    float* qkv      = (float*)(ws);
    float* y        = (float*)(ws);
    short* y_pk     = (short*)(ws + 32 * MiB);
    short* Wproj_pk = (short*)(ws + 64 * MiB);
    short* qt  = (short*)(ws + 128 * MiB);
    short* ktp = (short*)(ws + 144 * MiB);
    short* vtt = (short*)(ws + 160 * MiB);
    float* itp = (float*)(ws + 176 * MiB);
    short* x_pk     = (short*)(ws + 128 * MiB);
    short* Wqkv_pk  = (short*)(ws + 144 * MiB);

    // ---- stage A: qkv = x @ Wqkv (256x256 tile, phase-scheduled pipeline) ----
    prep_a<<<dim3(64, 32), 256, 0, stream>>>(x, x_pk, 2048, 0);
    prep_b<<<dim3(64, 64), 256, 0, stream>>>(Wqkv, Wqkv_pk, 2048, 8192, 0);
    gemm_bf16_256<2><<<dim3(512), 512, 0, stream>>>(x_pk, Wqkv_pk, qkv, 8192, 16, 64, 64, 64, 0);

    // ---- stage B: conv + rmsnorm + rope -> bf16 q,k,V^T + fp32 intent ----
    conv_norm_rope<<<dim3(T_SEQ, NH, 2), 128, 0, stream>>>(
        qkv, wq, wk, wv, wi, qnw, knw, cosT, sinT, qt, ktp, vtt, itp);

    // ---- stage C: bf16 MFMA flash attention + sigmoid gate ----
    flash_mfma<<<dim3(32 * 32), 256, 0, stream>>>(qt, ktp, vtt, itp, y);

    // ---- stage D: out = y @ Wproj (2-term split: y_hi @ [Whi|Wlo], K'=128) ----
    prep_a<<<dim3(64, 32), 256, 0, stream>>>(y, y_pk, 2048, 0);
    prep_b<<<dim3(64, 16), 256, 0, stream>>>(Wproj, Wproj_pk, 2048, 2048, 1);
    gemm_bf16_256<1><<<dim3(256), 512, 0, stream>>>(y_pk, Wproj_pk, out, 2048, 16, 64, 128, 128, 2);
}

// Round 8
// 412.011 us; speedup vs baseline: 1.2560x; 1.2560x over previous
//
#include <hip/hip_runtime.h>
#include <stdint.h>

#define T_SEQ 2048
#define C_DIM 2048
#define NH    16
#define HD    128
#define TT    32

typedef __attribute__((ext_vector_type(8))) short short8;
typedef __attribute__((ext_vector_type(4))) float f32x4;

#if defined(__has_builtin)
# if __has_builtin(__builtin_amdgcn_global_load_lds)
#  define HAVE_GLL 1
# endif
#endif
#ifndef HAVE_GLL
# define HAVE_GLL 0
#endif

__device__ __forceinline__ short f2bf(float f) {
    uint32_t x = __float_as_uint(f);
    uint32_t r = (x + 0x7fffu + ((x >> 16) & 1u)) >> 16;   // RNE
    return (short)r;
}
__device__ __forceinline__ float bf2f(short s) {
    return __uint_as_float(((uint32_t)(unsigned short)s) << 16);
}

// async global->LDS, 16B/lane; LDS dst is wave-uniform base, HW adds lane*16.
__device__ __forceinline__ void gload16(const short* g, short* l) {
    const int lane = threadIdx.x & 63;
#if HAVE_GLL
    __builtin_amdgcn_global_load_lds(
        (const __attribute__((address_space(1))) void*)(g + lane * 8),
        (__attribute__((address_space(3))) void*)l, 16, 0, 0);
#else
    *(short8*)(l + lane * 8) = *(const short8*)(g + lane * 8);
#endif
}

// ============ prep A-side: fp32 [M][K] -> fragment-ordered bf16 tiles ============
__global__ __launch_bounds__(256) void prep_a(
    const float* __restrict__ X, short* __restrict__ Apk, int K, int split)
{
    const int kb = blockIdx.x, mblk = blockIdx.y, tid = threadIdx.x;
    const int kpb = K / 32;
    const int nkb = kpb << split;
    const size_t hiBase = ((size_t)mblk * nkb + kb) * 4096;
    const size_t loBase = hiBase + (size_t)kpb * 4096;
#pragma unroll
    for (int itr = 0; itr < 2; ++itr) {
        const int item = itr * 256 + tid;
        const int row = item >> 2, kc = item & 3;
        const float* xp = &X[(size_t)(mblk * 128 + row) * K + kb * 32 + kc * 8];
        float4 v0 = *(const float4*)xp;
        float4 v1 = *(const float4*)(xp + 4);
        float f[8] = { v0.x, v0.y, v0.z, v0.w, v1.x, v1.y, v1.z, v1.w };
        const size_t off = (size_t)(row >> 4) * 512 + (size_t)((kc << 4) | (row & 15)) * 8;
        short h[8];
#pragma unroll
        for (int j = 0; j < 8; ++j) h[j] = f2bf(f[j]);
        int hw[4];
#pragma unroll
        for (int j = 0; j < 4; ++j) hw[j] = (h[2*j] & 0xffff) | (h[2*j+1] << 16);
        *(int4*)&Apk[hiBase + off] = make_int4(hw[0], hw[1], hw[2], hw[3]);
        if (split) {
            int lw[4];
#pragma unroll
            for (int j = 0; j < 4; ++j) {
                short a = f2bf(f[2*j]   - bf2f(h[2*j]));
                short b = f2bf(f[2*j+1] - bf2f(h[2*j+1]));
                lw[j] = (a & 0xffff) | (b << 16);
            }
            *(int4*)&Apk[loBase + off] = make_int4(lw[0], lw[1], lw[2], lw[3]);
        }
    }
}

// ============ prep B-side: fp32 [K][N] -> fragment-ordered bf16 tiles (transposed) ============
__global__ __launch_bounds__(256) void prep_b(
    const float* __restrict__ W, short* __restrict__ Bpk, int K, int N, int split)
{
    const int kb = blockIdx.x, nblk = blockIdx.y, tid = threadIdx.x;
    const int kpb = K / 32;
    const int nkb = kpb << split;
    __shared__ float Ws[32][129];
    {
        const int r = tid >> 3, cbase = (tid & 7) * 4;
#pragma unroll
        for (int itc = 0; itc < 4; ++itc) {
            const int c = cbase + itc * 32;
            const float4 v = *(const float4*)&W[(size_t)(kb * 32 + r) * N + nblk * 128 + c];
            Ws[r][c] = v.x; Ws[r][c + 1] = v.y; Ws[r][c + 2] = v.z; Ws[r][c + 3] = v.w;
        }
    }
    __syncthreads();
    const size_t hiBase = ((size_t)nblk * nkb + kb) * 4096;
    const size_t loBase = hiBase + (size_t)kpb * 4096;
#pragma unroll
    for (int itr = 0; itr < 2; ++itr) {
        const int item = itr * 256 + tid;
        const int n = item >> 2, kc = item & 3;
        float f[8];
#pragma unroll
        for (int j = 0; j < 8; ++j) f[j] = Ws[kc * 8 + j][n];
        const size_t off = (size_t)(n >> 4) * 512 + (size_t)((kc << 4) | (n & 15)) * 8;
        short h[8];
#pragma unroll
        for (int j = 0; j < 8; ++j) h[j] = f2bf(f[j]);
        int hw[4];
#pragma unroll
        for (int j = 0; j < 4; ++j) hw[j] = (h[2*j] & 0xffff) | (h[2*j+1] << 16);
        *(int4*)&Bpk[hiBase + off] = make_int4(hw[0], hw[1], hw[2], hw[3]);
        if (split) {
            int lw[4];
#pragma unroll
            for (int j = 0; j < 4; ++j) {
                short a = f2bf(f[2*j]   - bf2f(h[2*j]));
                short b = f2bf(f[2*j+1] - bf2f(h[2*j+1]));
                lw[j] = (a & 0xffff) | (b << 16);
            }
            *(int4*)&Bpk[loBase + off] = make_int4(lw[0], lw[1], lw[2], lw[3]);
        }
    }
}

// ============ bf16 MFMA GEMM: round-6 proven schedule (ring-4 DMA, 1 barrier + counted vmcnt/step) ====
// BM=256, BN=128*BNP, BK=32/step, 8 waves. Per step: vmcnt(N) -> barrier -> ds_reads ->
// stage(t+3) -> setprio(1) MFMA setprio(0). Fragment-ordered tiles => lane-linear ds_read_b128.
// mode: 0 = plain bf16; 2 = 2-term split (Ahi@[Bhi|Blo], nkb=128, A hi-only).
// Race proof: slot (t+3)&3 == (t-1)&3; every wave consumed slot t-1 into regs (lgkm-gated
// before its MFMAs) before reaching barrier(t); stage(t+3) issued after barrier(t).
template<int BNP>
__global__ __launch_bounds__(512, 2) void gemm_bf16_256(
    const short* __restrict__ Apk, const short* __restrict__ Bpk,
    float* __restrict__ C, int N, int gy, int nkbA, int nkbB, int nkb, int mode)
{
    constexpr int NT    = 2 + BNP;
    constexpr int STEPB = NT * 8192;
    constexpr int MR    = 4 * BNP;
    constexpr int WC    = 2 * BNP;
    __shared__ __align__(16) char smem[4 * STEPB];

    const int tid = threadIdx.x;
    const int lane = tid & 63, w = tid >> 6;
    const int r16 = lane & 15;
    const int wr = w / WC, wc = w % WC;

    const int nwg = gridDim.x, cpx = nwg >> 3, bid = blockIdx.x;
    const int swz = (bid & 7) * cpx + (bid >> 3);
    const int by = swz % gy, bx = swz / gy;
    const int bm = by * 256, bn = bx * (BNP * 128);
    const size_t Abase = (size_t)(2 * by) * nkbA * 4096;
    const size_t Bbase = (size_t)(BNP * bx) * nkbB * 4096;

    f32x4 acc[MR][4];
#pragma unroll
    for (int m = 0; m < MR; ++m)
#pragma unroll
        for (int n = 0; n < 4; ++n) acc[m][n] = (f32x4){0.f, 0.f, 0.f, 0.f};

    auto stage = [&](int vkb) {
        const int bi = vkb & 3;
        int akb, bkb;
        if (mode == 2)      { akb = (vkb < 64) ? vkb : vkb - 64; bkb = vkb; }
        else                { akb = vkb; bkb = vkb; }
#pragma unroll
        for (int i = 0; i < NT; ++i) {
            const int o = (w * NT + i) * 1024;
            const int tileIdx = o >> 13;
            const int inTile = (o & 8191) >> 1;
            const short* g = (tileIdx < 2)
                ? Apk + Abase + ((size_t)tileIdx * nkbA + akb) * 4096 + inTile
                : Bpk + Bbase + ((size_t)(tileIdx - 2) * nkbB + bkb) * 4096 + inTile;
            gload16(g, (short*)(smem + bi * STEPB + o));
        }
    };

    stage(0); stage(1); stage(2);
    __builtin_amdgcn_sched_barrier(0);

    for (int t = 0; t < nkb; ++t) {
        const int rem = nkb - 1 - t;
        if (BNP == 2) {
            if (rem >= 2)      asm volatile("s_waitcnt vmcnt(8)" ::: "memory");
            else if (rem == 1) asm volatile("s_waitcnt vmcnt(4)" ::: "memory");
            else               asm volatile("s_waitcnt vmcnt(0)" ::: "memory");
        } else {
            if (rem >= 2)      asm volatile("s_waitcnt vmcnt(6)" ::: "memory");
            else if (rem == 1) asm volatile("s_waitcnt vmcnt(3)" ::: "memory");
            else               asm volatile("s_waitcnt vmcnt(0)" ::: "memory");
        }
        __builtin_amdgcn_s_barrier();
        __builtin_amdgcn_sched_barrier(0);

        const char* buf = smem + (t & 3) * STEPB;
        short8 af[MR], bfr[4];
#pragma unroll
        for (int n = 0; n < 4; ++n) {
            const int fn = wc * 4 + n;
            bfr[n] = *(const short8*)(buf + 16384 + (fn >> 3) * 8192 + (fn & 7) * 1024 + lane * 16);
        }
#pragma unroll
        for (int m = 0; m < MR; ++m) {
            const int fm = wr * MR + m;
            af[m] = *(const short8*)(buf + (fm >> 3) * 8192 + (fm & 7) * 1024 + lane * 16);
        }
        if (t + 3 < nkb) stage(t + 3);

        __builtin_amdgcn_s_setprio(1);
#pragma unroll
        for (int m = 0; m < MR; ++m)
#pragma unroll
            for (int n = 0; n < 4; ++n)
                acc[m][n] = __builtin_amdgcn_mfma_f32_16x16x32_bf16(af[m], bfr[n], acc[m][n], 0, 0, 0);
        __builtin_amdgcn_s_setprio(0);
    }

    // ---- epilogue: per-wave private LDS bounce (stride 68), float4 coalesced stores ----
    __builtin_amdgcn_s_barrier();
    float* Cs = (float*)(smem + w * 4352);
    const int rq = lane >> 4;
#pragma unroll
    for (int m = 0; m < MR; ++m) {
#pragma unroll
        for (int n = 0; n < 4; ++n)
#pragma unroll
            for (int j = 0; j < 4; ++j)
                Cs[(rq * 4 + j) * 68 + n * 16 + r16] = acc[m][n][j];
#pragma unroll
        for (int it2 = 0; it2 < 4; ++it2) {
            const int r = it2 * 4 + rq;
            const float4 v = *(const float4*)&Cs[r * 68 + r16 * 4];
            const int grow = bm + wr * (MR * 16) + m * 16 + r;
            *(float4*)&C[(size_t)grow * N + bn + wc * 64 + r16 * 4] = v;
        }
    }
}

// ===================== conv3 + rmsnorm + rope, t-tiled (TT rows/block, rolling taps) ==========
// One pass over qkv (no 3x tap re-read); V^T staged in padded LDS, written as coalesced short8.
__global__ __launch_bounds__(128) void conv_norm_rope(
    const float* __restrict__ qkv,
    const float* __restrict__ wq, const float* __restrict__ wk,
    const float* __restrict__ wv, const float* __restrict__ wi,
    const float* __restrict__ qnw, const float* __restrict__ knw,
    const float* __restrict__ cosT, const float* __restrict__ sinT,
    short* __restrict__ qt, short* __restrict__ kt,
    short* __restrict__ vtt, float* __restrict__ it)
{
    const int tb = blockIdx.x, h = blockIdx.y, b = blockIdx.z;
    const int d = threadIdx.x;
    const int c = h * HD + d;
    const int t0 = tb * TT;

    __shared__ float red[2][4];
    __shared__ short vt_s[128][36];     // stride 36 shorts (72B): scalar writes <=2-way, int2 reads ok

    float w0[4], w1[4], w2[4];
    {
        const float* Wt[4] = { wq, wk, wv, wi };
#pragma unroll
        for (int s = 0; s < 4; ++s) {
            const float* wp = Wt[s] + c * 3;
            w0[s] = wp[0]; w1[s] = wp[1]; w2[s] = wp[2];
        }
    }
    const float qw = qnw[d], kw = knw[d];

    float xm1[4], xm2[4];
#pragma unroll
    for (int s = 0; s < 4; ++s) {
        xm1[s] = (t0 >= 1) ? qkv[((size_t)(b * T_SEQ + t0 - 1)) * (4 * C_DIM) + s * C_DIM + c] : 0.f;
        xm2[s] = (t0 >= 2) ? qkv[((size_t)(b * T_SEQ + t0 - 2)) * (4 * C_DIM) + s * C_DIM + c] : 0.f;
    }

    const int wid = d >> 6, lane = d & 63;

    for (int tt = 0; tt < TT; ++tt) {
        const int t = t0 + tt;
        const size_t rowbase = ((size_t)(b * T_SEQ + t)) * (4 * C_DIM);
        float x0[4], z[4];
#pragma unroll
        for (int s = 0; s < 4; ++s) x0[s] = qkv[rowbase + s * C_DIM + c];
#pragma unroll
        for (int s = 0; s < 4; ++s) {
            z[s] = fmaf(w0[s], xm2[s], fmaf(w1[s], xm1[s], w2[s] * x0[s]));
            xm2[s] = xm1[s]; xm1[s] = x0[s];
        }

        float sq = z[0] * z[0], sk = z[1] * z[1];
#pragma unroll
        for (int off = 32; off > 0; off >>= 1) {
            sq += __shfl_down(sq, off);
            sk += __shfl_down(sk, off);
        }
        const int pb = tt & 1;
        if (lane == 0) { red[pb][wid * 2 + 0] = sq; red[pb][wid * 2 + 1] = sk; }
        __syncthreads();
        // safe: reader of red[pb] finishes before sync(tt+1); next writer of red[pb] is
        // iter tt+2, after sync(tt+1) => ordered.
        const float rq = rsqrtf((red[pb][0] + red[pb][2]) * (1.f / HD) + 1e-5f);
        const float rk = rsqrtf((red[pb][1] + red[pb][3]) * (1.f / HD) + 1e-5f);

        float zq = z[0] * rq * qw;
        float zk = z[1] * rk * kw;
        float pq = __shfl_xor(zq, 1);
        float pk = __shfl_xor(zk, 1);
        const float cv = cosT[t * (HD / 2) + (d >> 1)];
        const float sv = sinT[t * (HD / 2) + (d >> 1)];
        float oq = (d & 1) ? (pq * sv + zq * cv) : (zq * cv - pq * sv);
        float ok = (d & 1) ? (pk * sv + zk * cv) : (zk * cv - pk * sv);
        oq *= 0.08838834764831845f;   // fold 1/sqrt(128) into q

        const size_t o = ((size_t)(b * NH + h) * T_SEQ + t) * HD + d;
        qt[o] = f2bf(oq);
        kt[o] = f2bf(ok);
        it[o] = z[3];
        vt_s[d][tt] = f2bf(z[2]);
    }
    __syncthreads();

    // V^T writeout: thread d owns row d -> 32 consecutive t = 64B coalesced store
    short vrow[TT];
#pragma unroll
    for (int i = 0; i < TT / 4; ++i)
        *(int2*)&vrow[i * 4] = *(const int2*)&vt_s[d][i * 4];
    short* dst = &vtt[((size_t)(b * NH + h) * HD + d) * T_SEQ + t0];
#pragma unroll
    for (int i = 0; i < TT / 8; ++i)
        *(short8*)(dst + i * 8) = *(const short8*)&vrow[i * 8];
}

// ===================== bf16 MFMA causal flash attention + sigmoid gate =====================
// + T14 async-stage split: K/V tile kti+1 global->reg issued before QK^T of tile kti,
//   LDS-write after the next barrier (HBM latency hides under QK^T/softmax/PV).
// + T13 defer-max: skip O-rescale when __all(mx <= m+8)  (P bounded by e^8, f32 accum ok).
__global__ __launch_bounds__(256, 3) void flash_mfma(
    const short* __restrict__ qt, const short* __restrict__ kt,
    const short* __restrict__ vtt, const float* __restrict__ it,
    float* __restrict__ y)
{
    __shared__ short lds_k[8192];
    __shared__ short lds_v[8192];
    __shared__ short lds_p[4096];

    const int tid = threadIdx.x;
    const int lane = tid & 63, w = tid >> 6;
    const int r16 = lane & 15, g = lane >> 4;

    const int blk = blockIdx.x;
    const int xcd = blk & 7, idx = blk >> 3;
    const int bh = xcd * 4 + (idx & 3);
    const int qt_i = 31 - (idx >> 2);
    const int b = bh >> 4, h = bh & 15;
    const int q0 = qt_i * 64;
    const int qrow = q0 + w * 16;

    char* KsB = (char*)lds_k;
    char* VsB = (char*)lds_v;
    char* PsB = (char*)lds_p + w * 2048;

    short8 qf[4];
    {
        const short* qp = qt + ((size_t)bh * T_SEQ + qrow + r16) * HD;
#pragma unroll
        for (int kc = 0; kc < 4; ++kc)
            qf[kc] = *(const short8*)(qp + kc * 32 + g * 8);
    }

    f32x4 o[8];
    float m[4], l[4];
#pragma unroll
    for (int dn = 0; dn < 8; ++dn) o[dn] = (f32x4){0.f, 0.f, 0.f, 0.f};
#pragma unroll
    for (int j = 0; j < 4; ++j) { m[j] = -1e30f; l[j] = 0.f; }

    const short* kbh = kt + (size_t)bh * T_SEQ * HD;
    const short* vbh = vtt + (size_t)bh * HD * T_SEQ;

    // per-thread staging coords
    const int krow = tid >> 4,  kdch = tid & 15;    // K: 4 chunks of (row, dch)
    const int vdr  = tid >> 3,  vkch = tid & 7;     // V: 4 chunks of (dr, kch)

    // prologue: load tile 0 into regs
    short8 kreg[4], vreg[4];
#pragma unroll
    for (int i = 0; i < 4; ++i) {
        kreg[i] = *(const short8*)(kbh + (size_t)(krow + i * 16) * HD + kdch * 8);
        vreg[i] = *(const short8*)(vbh + (size_t)(vdr + i * 32) * T_SEQ + vkch * 8);
    }

    for (int kti = 0; kti <= qt_i; ++kti) {
        __syncthreads();   // previous iteration's LDS reads complete
        // write staged tile kti (vmcnt auto-inserted on kreg/vreg use)
#pragma unroll
        for (int i = 0; i < 4; ++i) {
            const int row = krow + i * 16;
            *(short8*)(KsB + row * 256 + ((kdch * 16) ^ ((row & 7) << 4))) = kreg[i];
            const int dr = vdr + i * 32;
            *(short8*)(VsB + dr * 128 + ((vkch * 16) ^ ((dr & 7) << 4))) = vreg[i];
        }
        // issue next tile's loads now; they complete under QK^T/softmax/PV
        if (kti < qt_i) {
            const int k1 = (kti + 1) * 64;
#pragma unroll
            for (int i = 0; i < 4; ++i) {
                kreg[i] = *(const short8*)(kbh + (size_t)(k1 + krow + i * 16) * HD + kdch * 8);
                vreg[i] = *(const short8*)(vbh + (size_t)(vdr + i * 32) * T_SEQ + k1 + vkch * 8);
            }
        }
        __syncthreads();

        const int k0 = kti * 64;
        f32x4 sacc[4];
#pragma unroll
        for (int nt = 0; nt < 4; ++nt) sacc[nt] = (f32x4){0.f, 0.f, 0.f, 0.f};
        __builtin_amdgcn_s_setprio(1);
#pragma unroll
        for (int nt = 0; nt < 4; ++nt) {
            const int key = nt * 16 + r16;
#pragma unroll
            for (int kc = 0; kc < 4; ++kc) {
                const short8 kf = *(const short8*)(KsB + key * 256 +
                                    ((kc * 64 + g * 16) ^ ((r16 & 7) << 4)));
                sacc[nt] = __builtin_amdgcn_mfma_f32_16x16x32_bf16(qf[kc], kf, sacc[nt], 0, 0, 0);
            }
        }
        __builtin_amdgcn_s_setprio(0);

        const bool diag = (kti == qt_i);
#pragma unroll
        for (int j = 0; j < 4; ++j) {
            const int qi = qrow + g * 4 + j;
            float s0 = sacc[0][j], s1 = sacc[1][j], s2 = sacc[2][j], s3 = sacc[3][j];
            if (diag) {
                if (k0 +      r16 > qi) s0 = -1e30f;
                if (k0 + 16 + r16 > qi) s1 = -1e30f;
                if (k0 + 32 + r16 > qi) s2 = -1e30f;
                if (k0 + 48 + r16 > qi) s3 = -1e30f;
            }
            float mx = fmaxf(fmaxf(s0, s1), fmaxf(s2, s3));
            mx = fmaxf(mx, __shfl_xor(mx, 1));
            mx = fmaxf(mx, __shfl_xor(mx, 2));
            mx = fmaxf(mx, __shfl_xor(mx, 4));
            mx = fmaxf(mx, __shfl_xor(mx, 8));
            // T13 defer-max: only rescale when the max moved materially
            if (!__all(mx <= m[j] + 8.f)) {
                const float mn = fmaxf(m[j], mx);
                const float corr = __expf(m[j] - mn);
                m[j] = mn;
                l[j] *= corr;
#pragma unroll
                for (int dn = 0; dn < 8; ++dn) o[dn][j] *= corr;
            }
            float p0 = __expf(s0 - m[j]), p1 = __expf(s1 - m[j]);
            float p2 = __expf(s2 - m[j]), p3 = __expf(s3 - m[j]);
            float ps = p0 + p1 + p2 + p3;
            ps += __shfl_xor(ps, 1);
            ps += __shfl_xor(ps, 2);
            ps += __shfl_xor(ps, 4);
            ps += __shfl_xor(ps, 8);
            l[j] += ps;
            const int row = g * 4 + j;
            const int rsw = (row & 7) << 4;
            *(short*)(PsB + row * 128 + ((0  + r16 * 2) ^ rsw)) = f2bf(p0);
            *(short*)(PsB + row * 128 + ((32 + r16 * 2) ^ rsw)) = f2bf(p1);
            *(short*)(PsB + row * 128 + ((64 + r16 * 2) ^ rsw)) = f2bf(p2);
            *(short*)(PsB + row * 128 + ((96 + r16 * 2) ^ rsw)) = f2bf(p3);
        }

        short8 pf[2];
#pragma unroll
        for (int kc2 = 0; kc2 < 2; ++kc2)
            pf[kc2] = *(const short8*)(PsB + r16 * 128 +
                        ((kc2 * 64 + g * 16) ^ ((r16 & 7) << 4)));
        __builtin_amdgcn_s_setprio(1);
#pragma unroll
        for (int dn = 0; dn < 8; ++dn) {
            const int d = dn * 16 + r16;
#pragma unroll
            for (int kc2 = 0; kc2 < 2; ++kc2) {
                const short8 vf = *(const short8*)(VsB + d * 128 +
                                    ((kc2 * 64 + g * 16) ^ ((r16 & 7) << 4)));
                o[dn] = __builtin_amdgcn_mfma_f32_16x16x32_bf16(pf[kc2], vf, o[dn], 0, 0, 0);
            }
        }
        __builtin_amdgcn_s_setprio(0);
    }

#pragma unroll
    for (int j = 0; j < 4; ++j) {
        const float inv = 1.f / l[j];
        const int t = qrow + g * 4 + j;
        const float* ip = it + ((size_t)bh * T_SEQ + t) * HD;
        float* yp = y + ((size_t)(b * T_SEQ + t)) * C_DIM + h * HD;
#pragma unroll
        for (int dn = 0; dn < 8; ++dn) {
            const int d = dn * 16 + r16;
            const float gate = 1.f / (1.f + __expf(-ip[d]));
            yp[d] = o[dn][j] * inv * gate;
        }
    }
}

// ===================== launch =====================
extern "C" void kernel_launch(void* const* d_in, const int* in_sizes, int n_in,
                              void* d_out, int out_size, void* d_ws, size_t ws_size,
                              hipStream_t stream)
{
    const float* x     = (const float*)d_in[0];
    const float* cosT  = (const float*)d_in[1];
    const float* sinT  = (const float*)d_in[2];
    const float* Wqkv  = (const float*)d_in[3];
    const float* wq    = (const float*)d_in[4];
    const float* wk    = (const float*)d_in[5];
    const float* wv    = (const float*)d_in[6];
    const float* wi    = (const float*)d_in[7];
    const float* qnw   = (const float*)d_in[8];
    const float* knw   = (const float*)d_in[9];
    const float* Wproj = (const float*)d_in[10];
    float* out = (float*)d_out;

    char* ws = (char*)d_ws;
    const size_t MiB = 1048576;
    float* qkv      = (float*)(ws);
    float* y        = (float*)(ws);
    short* y_pk     = (short*)(ws + 32 * MiB);
    short* Wproj_pk = (short*)(ws + 64 * MiB);
    short* qt  = (short*)(ws + 128 * MiB);
    short* ktp = (short*)(ws + 144 * MiB);
    short* vtt = (short*)(ws + 160 * MiB);
    float* itp = (float*)(ws + 176 * MiB);
    short* x_pk     = (short*)(ws + 128 * MiB);
    short* Wqkv_pk  = (short*)(ws + 144 * MiB);

    // ---- stage A: qkv = x @ Wqkv (round-6 schedule) ----
    prep_a<<<dim3(64, 32), 256, 0, stream>>>(x, x_pk, 2048, 0);
    prep_b<<<dim3(64, 64), 256, 0, stream>>>(Wqkv, Wqkv_pk, 2048, 8192, 0);
    gemm_bf16_256<2><<<dim3(512), 512, 0, stream>>>(x_pk, Wqkv_pk, qkv, 8192, 16, 64, 64, 64, 0);

    // ---- stage B: conv + rmsnorm + rope, t-tiled ----
    conv_norm_rope<<<dim3(T_SEQ / TT, NH, 2), 128, 0, stream>>>(
        qkv, wq, wk, wv, wi, qnw, knw, cosT, sinT, qt, ktp, vtt, itp);

    // ---- stage C: bf16 MFMA flash attention (async-stage + defer-max) ----
    flash_mfma<<<dim3(32 * 32), 256, 0, stream>>>(qt, ktp, vtt, itp, y);

    // ---- stage D: out = y @ Wproj (2-term split: y_hi @ [Whi|Wlo], K'=128) ----
    prep_a<<<dim3(64, 32), 256, 0, stream>>>(y, y_pk, 2048, 0);
    prep_b<<<dim3(64, 16), 256, 0, stream>>>(Wproj, Wproj_pk, 2048, 2048, 1);
    gemm_bf16_256<1><<<dim3(256), 512, 0, stream>>>(y_pk, Wproj_pk, out, 2048, 16, 64, 128, 128, 2);
}

// Round 9
// 405.506 us; speedup vs baseline: 1.2762x; 1.0160x over previous
//
#include <hip/hip_runtime.h>
#include <stdint.h>

#define T_SEQ 2048
#define C_DIM 2048
#define NH    16
#define HD    128
#define TT    32

typedef __attribute__((ext_vector_type(8))) short short8;
typedef __attribute__((ext_vector_type(4))) float f32x4;

#if defined(__has_builtin)
# if __has_builtin(__builtin_amdgcn_global_load_lds)
#  define HAVE_GLL 1
# endif
#endif
#ifndef HAVE_GLL
# define HAVE_GLL 0
#endif

__device__ __forceinline__ short f2bf(float f) {
    uint32_t x = __float_as_uint(f);
    uint32_t r = (x + 0x7fffu + ((x >> 16) & 1u)) >> 16;   // RNE
    return (short)r;
}
__device__ __forceinline__ float bf2f(short s) {
    return __uint_as_float(((uint32_t)(unsigned short)s) << 16);
}

// async global->LDS, 16B/lane; LDS dst is wave-uniform base, HW adds lane*16.
__device__ __forceinline__ void gload16(const short* g, short* l) {
    const int lane = threadIdx.x & 63;
#if HAVE_GLL
    __builtin_amdgcn_global_load_lds(
        (const __attribute__((address_space(1))) void*)(g + lane * 8),
        (__attribute__((address_space(3))) void*)l, 16, 0, 0);
#else
    *(short8*)(l + lane * 8) = *(const short8*)(g + lane * 8);
#endif
}

// ============ prep A-side: fp32 [M][K] -> fragment-ordered bf16 tiles ============
__global__ __launch_bounds__(256) void prep_a(
    const float* __restrict__ X, short* __restrict__ Apk, int K, int split)
{
    const int kb = blockIdx.x, mblk = blockIdx.y, tid = threadIdx.x;
    const int kpb = K / 32;
    const int nkb = kpb << split;
    const size_t hiBase = ((size_t)mblk * nkb + kb) * 4096;
    const size_t loBase = hiBase + (size_t)kpb * 4096;
#pragma unroll
    for (int itr = 0; itr < 2; ++itr) {
        const int item = itr * 256 + tid;
        const int row = item >> 2, kc = item & 3;
        const float* xp = &X[(size_t)(mblk * 128 + row) * K + kb * 32 + kc * 8];
        float4 v0 = *(const float4*)xp;
        float4 v1 = *(const float4*)(xp + 4);
        float f[8] = { v0.x, v0.y, v0.z, v0.w, v1.x, v1.y, v1.z, v1.w };
        const size_t off = (size_t)(row >> 4) * 512 + (size_t)((kc << 4) | (row & 15)) * 8;
        short h[8];
#pragma unroll
        for (int j = 0; j < 8; ++j) h[j] = f2bf(f[j]);
        int hw[4];
#pragma unroll
        for (int j = 0; j < 4; ++j) hw[j] = (h[2*j] & 0xffff) | (h[2*j+1] << 16);
        *(int4*)&Apk[hiBase + off] = make_int4(hw[0], hw[1], hw[2], hw[3]);
        if (split) {
            int lw[4];
#pragma unroll
            for (int j = 0; j < 4; ++j) {
                short a = f2bf(f[2*j]   - bf2f(h[2*j]));
                short b = f2bf(f[2*j+1] - bf2f(h[2*j+1]));
                lw[j] = (a & 0xffff) | (b << 16);
            }
            *(int4*)&Apk[loBase + off] = make_int4(lw[0], lw[1], lw[2], lw[3]);
        }
    }
}

// ============ prep B-side: fp32 [K][N] -> fragment-ordered bf16 tiles (transposed) ============
__global__ __launch_bounds__(256) void prep_b(
    const float* __restrict__ W, short* __restrict__ Bpk, int K, int N, int split)
{
    const int kb = blockIdx.x, nblk = blockIdx.y, tid = threadIdx.x;
    const int kpb = K / 32;
    const int nkb = kpb << split;
    __shared__ float Ws[32][129];
    {
        const int r = tid >> 3, cbase = (tid & 7) * 4;
#pragma unroll
        for (int itc = 0; itc < 4; ++itc) {
            const int c = cbase + itc * 32;
            const float4 v = *(const float4*)&W[(size_t)(kb * 32 + r) * N + nblk * 128 + c];
            Ws[r][c] = v.x; Ws[r][c + 1] = v.y; Ws[r][c + 2] = v.z; Ws[r][c + 3] = v.w;
        }
    }
    __syncthreads();
    const size_t hiBase = ((size_t)nblk * nkb + kb) * 4096;
    const size_t loBase = hiBase + (size_t)kpb * 4096;
#pragma unroll
    for (int itr = 0; itr < 2; ++itr) {
        const int item = itr * 256 + tid;
        const int n = item >> 2, kc = item & 3;
        float f[8];
#pragma unroll
        for (int j = 0; j < 8; ++j) f[j] = Ws[kc * 8 + j][n];
        const size_t off = (size_t)(n >> 4) * 512 + (size_t)((kc << 4) | (n & 15)) * 8;
        short h[8];
#pragma unroll
        for (int j = 0; j < 8; ++j) h[j] = f2bf(f[j]);
        int hw[4];
#pragma unroll
        for (int j = 0; j < 4; ++j) hw[j] = (h[2*j] & 0xffff) | (h[2*j+1] << 16);
        *(int4*)&Bpk[hiBase + off] = make_int4(hw[0], hw[1], hw[2], hw[3]);
        if (split) {
            int lw[4];
#pragma unroll
            for (int j = 0; j < 4; ++j) {
                short a = f2bf(f[2*j]   - bf2f(h[2*j]));
                short b = f2bf(f[2*j+1] - bf2f(h[2*j+1]));
                lw[j] = (a & 0xffff) | (b << 16);
            }
            *(int4*)&Bpk[loBase + off] = make_int4(lw[0], lw[1], lw[2], lw[3]);
        }
    }
}

// ============ bf16 MFMA GEMM: BK=64 steps, ring-2 LDS, depth-1 prefetch (covered vmcnt(0)) ====
// BM=256, BN=128*BNP, 8 waves. Per step: vmcnt(0) -> barrier ->
//   {ds_read half0 | stage(t+1) | MFMA32 -> ds_read half1 | MFMA32}  (no intra-step barrier).
// Fixed per-step cost (LDS burst + barrier chain, ~1550cy measured r8) amortized over 2x MFMA.
// vmcnt(0) is covered: stage(t+1) issues mid-step t, awaited at t+1 (>=1500cy > 900cy HBM).
// Race proof: barrier(t) => all waves consumed buf[(t-1)&1] == buf[(t+1)&1]; DMA writes only that.
// mode: 0 = plain bf16; 2 = 2-term split (Ahi@[Bhi|Blo], A hi-only, nsteps=64).
template<int BNP>
__global__ __launch_bounds__(512, 2) void gemm_bf16_256(
    const short* __restrict__ Apk, const short* __restrict__ Bpk,
    float* __restrict__ C, int N, int gy, int nkbA, int nkbB, int nsteps, int mode)
{
    constexpr int NT2   = (2 + BNP) * 2;      // 8KB tiles per step: A 4, B 2*BNP
    constexpr int STEPB = NT2 * 8192;         // 64KB (BNP=2) / 48KB (BNP=1)
    constexpr int MR    = 4 * BNP;
    constexpr int WC    = 2 * BNP;
    __shared__ __align__(16) char smem[2 * STEPB];   // 128 KB / 96 KB

    const int tid = threadIdx.x;
    const int lane = tid & 63, w = tid >> 6;
    const int r16 = lane & 15;
    const int wr = w / WC, wc = w % WC;

    // bijective XCD swizzle (nwg % 8 == 0)
    const int nwg = gridDim.x, cpx = nwg >> 3, bid = blockIdx.x;
    const int swz = (bid & 7) * cpx + (bid >> 3);
    const int by = swz % gy, bx = swz / gy;
    const int bm = by * 256, bn = bx * (BNP * 128);
    const size_t Abase = (size_t)(2 * by) * nkbA * 4096;
    const size_t Bbase = (size_t)(BNP * bx) * nkbB * 4096;

    f32x4 acc[MR][4];
#pragma unroll
    for (int m = 0; m < MR; ++m)
#pragma unroll
        for (int n = 0; n < 4; ++n) acc[m][n] = (f32x4){0.f, 0.f, 0.f, 0.f};

    // stage step t into buf[t&1]: per wave NT2 x 1KB chunks (gload16 = 1KB/instr)
    auto stage = [&](int t) {
        const int bi = t & 1;
#pragma unroll
        for (int i = 0; i < NT2; ++i) {
            const int o = (w * NT2 + i) * 1024;      // byte offset in step buffer
            const int tileIdx = o >> 13;             // 8KB tiles: A = panel*2+h, B = 4 + q*2+h
            const int inTile = (o & 8191) >> 1;      // shorts
            const int h = tileIdx & 1;
            const int v = 2 * t + h;                 // kb32 index
            const short* g;
            if (tileIdx < 4) {
                const int akb = (mode == 2) ? (v & 63) : v;
                g = Apk + Abase + ((size_t)(tileIdx >> 1) * nkbA + akb) * 4096 + inTile;
            } else {
                g = Bpk + Bbase + ((size_t)((tileIdx - 4) >> 1) * nkbB + v) * 4096 + inTile;
            }
            gload16(g, (short*)(smem + bi * STEPB + o));
        }
    };

    stage(0);
    __builtin_amdgcn_sched_barrier(0);

    for (int t = 0; t < nsteps; ++t) {
        asm volatile("s_waitcnt vmcnt(0)" ::: "memory");   // buf[t&1] landed (this wave's DMA)
        __builtin_amdgcn_s_barrier();                      // all waves' DMA done + prev reads done
        __builtin_amdgcn_sched_barrier(0);
        const char* buf = smem + (t & 1) * STEPB;

#pragma unroll
        for (int h = 0; h < 2; ++h) {
            short8 af[MR], bfr[4];
#pragma unroll
            for (int n = 0; n < 4; ++n) {
                const int fn = wc * 4 + n;
                bfr[n] = *(const short8*)(buf + 32768 + ((fn >> 3) * 2 + h) * 8192
                                              + (fn & 7) * 1024 + lane * 16);
            }
#pragma unroll
            for (int m = 0; m < MR; ++m) {
                const int fm = wr * MR + m;
                af[m] = *(const short8*)(buf + ((fm >> 3) * 2 + h) * 8192
                                             + (fm & 7) * 1024 + lane * 16);
            }
            if (h == 0 && t + 1 < nsteps) stage(t + 1);    // DMA overlaps both MFMA halves

            __builtin_amdgcn_s_setprio(1);
#pragma unroll
            for (int m = 0; m < MR; ++m)
#pragma unroll
                for (int n = 0; n < 4; ++n)
                    acc[m][n] = __builtin_amdgcn_mfma_f32_16x16x32_bf16(af[m], bfr[n], acc[m][n], 0, 0, 0);
            __builtin_amdgcn_s_setprio(0);
        }
    }

    // ---- epilogue: per-wave private LDS bounce (stride 68), float4 coalesced stores ----
    __builtin_amdgcn_s_barrier();
    float* Cs = (float*)(smem + w * 4352);
    const int rq = lane >> 4;
#pragma unroll
    for (int m = 0; m < MR; ++m) {
#pragma unroll
        for (int n = 0; n < 4; ++n)
#pragma unroll
            for (int j = 0; j < 4; ++j)
                Cs[(rq * 4 + j) * 68 + n * 16 + r16] = acc[m][n][j];
#pragma unroll
        for (int it2 = 0; it2 < 4; ++it2) {
            const int r = it2 * 4 + rq;
            const float4 v = *(const float4*)&Cs[r * 68 + r16 * 4];
            const int grow = bm + wr * (MR * 16) + m * 16 + r;
            *(float4*)&C[(size_t)grow * N + bn + wc * 64 + r16 * 4] = v;
        }
    }
}

// ===================== conv3 + rmsnorm + rope, t-tiled (TT rows/block, rolling taps) ==========
__global__ __launch_bounds__(128) void conv_norm_rope(
    const float* __restrict__ qkv,
    const float* __restrict__ wq, const float* __restrict__ wk,
    const float* __restrict__ wv, const float* __restrict__ wi,
    const float* __restrict__ qnw, const float* __restrict__ knw,
    const float* __restrict__ cosT, const float* __restrict__ sinT,
    short* __restrict__ qt, short* __restrict__ kt,
    short* __restrict__ vtt, float* __restrict__ it)
{
    const int tb = blockIdx.x, h = blockIdx.y, b = blockIdx.z;
    const int d = threadIdx.x;
    const int c = h * HD + d;
    const int t0 = tb * TT;

    __shared__ float red[2][4];
    __shared__ short vt_s[128][36];

    float w0[4], w1[4], w2[4];
    {
        const float* Wt[4] = { wq, wk, wv, wi };
#pragma unroll
        for (int s = 0; s < 4; ++s) {
            const float* wp = Wt[s] + c * 3;
            w0[s] = wp[0]; w1[s] = wp[1]; w2[s] = wp[2];
        }
    }
    const float qw = qnw[d], kw = knw[d];

    float xm1[4], xm2[4];
#pragma unroll
    for (int s = 0; s < 4; ++s) {
        xm1[s] = (t0 >= 1) ? qkv[((size_t)(b * T_SEQ + t0 - 1)) * (4 * C_DIM) + s * C_DIM + c] : 0.f;
        xm2[s] = (t0 >= 2) ? qkv[((size_t)(b * T_SEQ + t0 - 2)) * (4 * C_DIM) + s * C_DIM + c] : 0.f;
    }

    const int wid = d >> 6, lane = d & 63;

    for (int tt = 0; tt < TT; ++tt) {
        const int t = t0 + tt;
        const size_t rowbase = ((size_t)(b * T_SEQ + t)) * (4 * C_DIM);
        float x0[4], z[4];
#pragma unroll
        for (int s = 0; s < 4; ++s) x0[s] = qkv[rowbase + s * C_DIM + c];
#pragma unroll
        for (int s = 0; s < 4; ++s) {
            z[s] = fmaf(w0[s], xm2[s], fmaf(w1[s], xm1[s], w2[s] * x0[s]));
            xm2[s] = xm1[s]; xm1[s] = x0[s];
        }

        float sq = z[0] * z[0], sk = z[1] * z[1];
#pragma unroll
        for (int off = 32; off > 0; off >>= 1) {
            sq += __shfl_down(sq, off);
            sk += __shfl_down(sk, off);
        }
        const int pb = tt & 1;
        if (lane == 0) { red[pb][wid * 2 + 0] = sq; red[pb][wid * 2 + 1] = sk; }
        __syncthreads();
        const float rq = rsqrtf((red[pb][0] + red[pb][2]) * (1.f / HD) + 1e-5f);
        const float rk = rsqrtf((red[pb][1] + red[pb][3]) * (1.f / HD) + 1e-5f);

        float zq = z[0] * rq * qw;
        float zk = z[1] * rk * kw;
        float pq = __shfl_xor(zq, 1);
        float pk = __shfl_xor(zk, 1);
        const float cv = cosT[t * (HD / 2) + (d >> 1)];
        const float sv = sinT[t * (HD / 2) + (d >> 1)];
        float oq = (d & 1) ? (pq * sv + zq * cv) : (zq * cv - pq * sv);
        float ok = (d & 1) ? (pk * sv + zk * cv) : (zk * cv - pk * sv);
        oq *= 0.08838834764831845f;

        const size_t o = ((size_t)(b * NH + h) * T_SEQ + t) * HD + d;
        qt[o] = f2bf(oq);
        kt[o] = f2bf(ok);
        it[o] = z[3];
        vt_s[d][tt] = f2bf(z[2]);
    }
    __syncthreads();

    short vrow[TT];
#pragma unroll
    for (int i = 0; i < TT / 4; ++i)
        *(int2*)&vrow[i * 4] = *(const int2*)&vt_s[d][i * 4];
    short* dst = &vtt[((size_t)(b * NH + h) * HD + d) * T_SEQ + t0];
#pragma unroll
    for (int i = 0; i < TT / 8; ++i)
        *(short8*)(dst + i * 8) = *(const short8*)&vrow[i * 8];
}

// ===================== bf16 MFMA causal flash attention + sigmoid gate =====================
__global__ __launch_bounds__(256, 3) void flash_mfma(
    const short* __restrict__ qt, const short* __restrict__ kt,
    const short* __restrict__ vtt, const float* __restrict__ it,
    float* __restrict__ y)
{
    __shared__ short lds_k[8192];
    __shared__ short lds_v[8192];
    __shared__ short lds_p[4096];

    const int tid = threadIdx.x;
    const int lane = tid & 63, w = tid >> 6;
    const int r16 = lane & 15, g = lane >> 4;

    const int blk = blockIdx.x;
    const int xcd = blk & 7, idx = blk >> 3;
    const int bh = xcd * 4 + (idx & 3);
    const int qt_i = 31 - (idx >> 2);
    const int b = bh >> 4, h = bh & 15;
    const int q0 = qt_i * 64;
    const int qrow = q0 + w * 16;

    char* KsB = (char*)lds_k;
    char* VsB = (char*)lds_v;
    char* PsB = (char*)lds_p + w * 2048;

    short8 qf[4];
    {
        const short* qp = qt + ((size_t)bh * T_SEQ + qrow + r16) * HD;
#pragma unroll
        for (int kc = 0; kc < 4; ++kc)
            qf[kc] = *(const short8*)(qp + kc * 32 + g * 8);
    }

    f32x4 o[8];
    float m[4], l[4];
#pragma unroll
    for (int dn = 0; dn < 8; ++dn) o[dn] = (f32x4){0.f, 0.f, 0.f, 0.f};
#pragma unroll
    for (int j = 0; j < 4; ++j) { m[j] = -1e30f; l[j] = 0.f; }

    const short* kbh = kt + (size_t)bh * T_SEQ * HD;
    const short* vbh = vtt + (size_t)bh * HD * T_SEQ;

    const int krow = tid >> 4,  kdch = tid & 15;
    const int vdr  = tid >> 3,  vkch = tid & 7;

    short8 kreg[4], vreg[4];
#pragma unroll
    for (int i = 0; i < 4; ++i) {
        kreg[i] = *(const short8*)(kbh + (size_t)(krow + i * 16) * HD + kdch * 8);
        vreg[i] = *(const short8*)(vbh + (size_t)(vdr + i * 32) * T_SEQ + vkch * 8);
    }

    for (int kti = 0; kti <= qt_i; ++kti) {
        __syncthreads();
#pragma unroll
        for (int i = 0; i < 4; ++i) {
            const int row = krow + i * 16;
            *(short8*)(KsB + row * 256 + ((kdch * 16) ^ ((row & 7) << 4))) = kreg[i];
            const int dr = vdr + i * 32;
            *(short8*)(VsB + dr * 128 + ((vkch * 16) ^ ((dr & 7) << 4))) = vreg[i];
        }
        if (kti < qt_i) {
            const int k1 = (kti + 1) * 64;
#pragma unroll
            for (int i = 0; i < 4; ++i) {
                kreg[i] = *(const short8*)(kbh + (size_t)(k1 + krow + i * 16) * HD + kdch * 8);
                vreg[i] = *(const short8*)(vbh + (size_t)(vdr + i * 32) * T_SEQ + k1 + vkch * 8);
            }
        }
        __syncthreads();

        const int k0 = kti * 64;
        f32x4 sacc[4];
#pragma unroll
        for (int nt = 0; nt < 4; ++nt) sacc[nt] = (f32x4){0.f, 0.f, 0.f, 0.f};
        __builtin_amdgcn_s_setprio(1);
#pragma unroll
        for (int nt = 0; nt < 4; ++nt) {
            const int key = nt * 16 + r16;
#pragma unroll
            for (int kc = 0; kc < 4; ++kc) {
                const short8 kf = *(const short8*)(KsB + key * 256 +
                                    ((kc * 64 + g * 16) ^ ((r16 & 7) << 4)));
                sacc[nt] = __builtin_amdgcn_mfma_f32_16x16x32_bf16(qf[kc], kf, sacc[nt], 0, 0, 0);
            }
        }
        __builtin_amdgcn_s_setprio(0);

        const bool diag = (kti == qt_i);
#pragma unroll
        for (int j = 0; j < 4; ++j) {
            const int qi = qrow + g * 4 + j;
            float s0 = sacc[0][j], s1 = sacc[1][j], s2 = sacc[2][j], s3 = sacc[3][j];
            if (diag) {
                if (k0 +      r16 > qi) s0 = -1e30f;
                if (k0 + 16 + r16 > qi) s1 = -1e30f;
                if (k0 + 32 + r16 > qi) s2 = -1e30f;
                if (k0 + 48 + r16 > qi) s3 = -1e30f;
            }
            float mx = fmaxf(fmaxf(s0, s1), fmaxf(s2, s3));
            mx = fmaxf(mx, __shfl_xor(mx, 1));
            mx = fmaxf(mx, __shfl_xor(mx, 2));
            mx = fmaxf(mx, __shfl_xor(mx, 4));
            mx = fmaxf(mx, __shfl_xor(mx, 8));
            if (!__all(mx <= m[j] + 8.f)) {
                const float mn = fmaxf(m[j], mx);
                const float corr = __expf(m[j] - mn);
                m[j] = mn;
                l[j] *= corr;
#pragma unroll
                for (int dn = 0; dn < 8; ++dn) o[dn][j] *= corr;
            }
            float p0 = __expf(s0 - m[j]), p1 = __expf(s1 - m[j]);
            float p2 = __expf(s2 - m[j]), p3 = __expf(s3 - m[j]);
            float ps = p0 + p1 + p2 + p3;
            ps += __shfl_xor(ps, 1);
            ps += __shfl_xor(ps, 2);
            ps += __shfl_xor(ps, 4);
            ps += __shfl_xor(ps, 8);
            l[j] += ps;
            const int row = g * 4 + j;
            const int rsw = (row & 7) << 4;
            *(short*)(PsB + row * 128 + ((0  + r16 * 2) ^ rsw)) = f2bf(p0);
            *(short*)(PsB + row * 128 + ((32 + r16 * 2) ^ rsw)) = f2bf(p1);
            *(short*)(PsB + row * 128 + ((64 + r16 * 2) ^ rsw)) = f2bf(p2);
            *(short*)(PsB + row * 128 + ((96 + r16 * 2) ^ rsw)) = f2bf(p3);
        }

        short8 pf[2];
#pragma unroll
        for (int kc2 = 0; kc2 < 2; ++kc2)
            pf[kc2] = *(const short8*)(PsB + r16 * 128 +
                        ((kc2 * 64 + g * 16) ^ ((r16 & 7) << 4)));
        __builtin_amdgcn_s_setprio(1);
#pragma unroll
        for (int dn = 0; dn < 8; ++dn) {
            const int d = dn * 16 + r16;
#pragma unroll
            for (int kc2 = 0; kc2 < 2; ++kc2) {
                const short8 vf = *(const short8*)(VsB + d * 128 +
                                    ((kc2 * 64 + g * 16) ^ ((r16 & 7) << 4)));
                o[dn] = __builtin_amdgcn_mfma_f32_16x16x32_bf16(pf[kc2], vf, o[dn], 0, 0, 0);
            }
        }
        __builtin_amdgcn_s_setprio(0);
    }

#pragma unroll
    for (int j = 0; j < 4; ++j) {
        const float inv = 1.f / l[j];
        const int t = qrow + g * 4 + j;
        const float* ip = it + ((size_t)bh * T_SEQ + t) * HD;
        float* yp = y + ((size_t)(b * T_SEQ + t)) * C_DIM + h * HD;
#pragma unroll
        for (int dn = 0; dn < 8; ++dn) {
            const int d = dn * 16 + r16;
            const float gate = 1.f / (1.f + __expf(-ip[d]));
            yp[d] = o[dn][j] * inv * gate;
        }
    }
}

// ===================== launch =====================
extern "C" void kernel_launch(void* const* d_in, const int* in_sizes, int n_in,
                              void* d_out, int out_size, void* d_ws, size_t ws_size,
                              hipStream_t stream)
{
    const float* x     = (const float*)d_in[0];
    const float* cosT  = (const float*)d_in[1];
    const float* sinT  = (const float*)d_in[2];
    const float* Wqkv  = (const float*)d_in[3];
    const float* wq    = (const float*)d_in[4];
    const float* wk    = (const float*)d_in[5];
    const float* wv    = (const float*)d_in[6];
    const float* wi    = (const float*)d_in[7];
    const float* qnw   = (const float*)d_in[8];
    const float* knw   = (const float*)d_in[9];
    const float* Wproj = (const float*)d_in[10];
    float* out = (float*)d_out;

    char* ws = (char*)d_ws;
    const size_t MiB = 1048576;
    float* qkv      = (float*)(ws);
    float* y        = (float*)(ws);
    short* y_pk     = (short*)(ws + 32 * MiB);
    short* Wproj_pk = (short*)(ws + 64 * MiB);
    short* qt  = (short*)(ws + 128 * MiB);
    short* ktp = (short*)(ws + 144 * MiB);
    short* vtt = (short*)(ws + 160 * MiB);
    float* itp = (float*)(ws + 176 * MiB);
    short* x_pk     = (short*)(ws + 128 * MiB);
    short* Wqkv_pk  = (short*)(ws + 144 * MiB);

    // ---- stage A: qkv = x @ Wqkv (BK=64 ring-2 schedule) ----
    prep_a<<<dim3(64, 32), 256, 0, stream>>>(x, x_pk, 2048, 0);
    prep_b<<<dim3(64, 64), 256, 0, stream>>>(Wqkv, Wqkv_pk, 2048, 8192, 0);
    gemm_bf16_256<2><<<dim3(512), 512, 0, stream>>>(x_pk, Wqkv_pk, qkv, 8192, 16, 64, 64, 32, 0);

    // ---- stage B: conv + rmsnorm + rope, t-tiled ----
    conv_norm_rope<<<dim3(T_SEQ / TT, NH, 2), 128, 0, stream>>>(
        qkv, wq, wk, wv, wi, qnw, knw, cosT, sinT, qt, ktp, vtt, itp);

    // ---- stage C: bf16 MFMA flash attention (async-stage + defer-max) ----
    flash_mfma<<<dim3(32 * 32), 256, 0, stream>>>(qt, ktp, vtt, itp, y);

    // ---- stage D: out = y @ Wproj (2-term split: y_hi @ [Whi|Wlo], 64 BK64-steps) ----
    prep_a<<<dim3(64, 32), 256, 0, stream>>>(y, y_pk, 2048, 0);
    prep_b<<<dim3(64, 16), 256, 0, stream>>>(Wproj, Wproj_pk, 2048, 2048, 1);
    gemm_bf16_256<1><<<dim3(256), 512, 0, stream>>>(y_pk, Wproj_pk, out, 2048, 16, 64, 128, 64, 2);
}